// Round 16
// baseline (355.168 us; speedup 1.0000x reference)
//
#include <hip/hip_runtime.h>
#include <math.h>

// Sizes fixed by the reference: B=512, T=1024, D_IN=D_OUT=64, H=256.
#define HDIM 256
#define DDIM 64
#define BROWS 512
#define TSTEPS 1024
// Augmented rows: 65 weight rows (t-row + 64 state rows) + 1 bias row.
#define AROWS 66

typedef float f32x2 __attribute__((ext_vector_type(2)));
typedef float f32x4 __attribute__((ext_vector_type(4)));

// ---- Setup: compose the linear MLP into one 66x64 affine map ----
__global__ void compose1(const float* __restrict__ W0, const float* __restrict__ b0,
                         const float* __restrict__ W1, const float* __restrict__ b1,
                         float* __restrict__ out1) {
    int r = blockIdx.x;    // 0..65
    int c = threadIdx.x;   // 0..255
    const float* arow = (r < 65) ? (W0 + r * HDIM) : b0;
    float acc = (r == 65) ? b1[c] : 0.0f;
    for (int h = 0; h < HDIM; ++h)
        acc = fmaf(arow[h], W1[h * HDIM + c], acc);
    out1[r * HDIM + c] = acc;
}

__global__ void compose2(const float* __restrict__ in1,
                         const float* __restrict__ W2, const float* __restrict__ b2,
                         float* __restrict__ out2) {
    int r = blockIdx.x, c = threadIdx.x;
    const float* arow = in1 + r * HDIM;
    float acc = (r == 65) ? b2[c] : 0.0f;
    for (int h = 0; h < HDIM; ++h)
        acc = fmaf(arow[h], W2[h * HDIM + c], acc);
    out2[r * HDIM + c] = acc;
}

__global__ void compose3(const float* __restrict__ in2,
                         const float* __restrict__ W3, const float* __restrict__ b3,
                         float* __restrict__ out3) {
    int r = blockIdx.x, c = threadIdx.x;   // c 0..63
    const float* arow = in2 + r * HDIM;
    float acc = (r == 65) ? b3[c] : 0.0f;
    for (int h = 0; h < HDIM; ++h)
        acc = fmaf(arow[h], W3[h * DDIM + c], acc);
    out3[r * DDIM + c] = acc;
}

// Packed 2xf32 FMA: acc.lo += a.lo*b.lo; acc.hi += a.hi*b.hi  (VOP3P, CDNA)
__device__ __forceinline__ void pkfma(f32x2& acc, f32x2 a, f32x2 b) {
    asm("v_pk_fma_f32 %0, %1, %2, %0" : "+v"(acc) : "v"(a), "v"(b));
}

// ---- Main scan: one wave per TWO batch rows, lane = output dim ----
//
// Model (r4..r15): per-step chain = tanh + DS read latency(~130)+drain(~96)
// + 32 pkfma + combine. Cross-lane reg ops cost ~10cyc each (r15), so the
// LDS half-split path (r14) stays; the ~215cyc of exposed DS latency is
// HIDDEN under a second row's compute via software pipelining:
//   issue wA,rA*8,wB,rB*8,p (19 counted DS ops) -> off-chain updates ->
//   lgkm(10): pkfmaA+combineA+sA+tanhA   (covers B's read latency)
//   lgkm(1):  pkfmaB+combineB+sB+tanhB
//   lgkm(0):  prm = prmn
// W is SHARED between the rows (only y,s,r,ptr duplicate). r15's proven
// weight folding (broadcast r=rcp(exp2(s)+1), W2s=-2*K2L*W, colsum Cd)
// keeps the y-update and the th-fma off the chain.
__launch_bounds__(64, 1)
__global__ void fode_scan(const float* __restrict__ x, const float* __restrict__ t,
                          const float* __restrict__ Weff,   // 66 x 64 composed
                          float* __restrict__ out) {
    const int bA = blockIdx.x * 2;      // rows bA, bA+1
    const int d  = threadIdx.x;         // 0..63

    __shared__ __align__(16) float yAl[DDIM];
    __shared__ __align__(16) float yBl[DDIM];
    __shared__ __align__(8)  float2 plds[TSTEPS];  // (dt_k, f_k); last unused

    const float invG = 0.56418958354775628695f;   // 1/Gamma(0.5)
    const float K2L = 2.88539008177792681472f;    // 2*log2(e)

    // Per-step params (dt, factor): coalesced staging, once per block.
    for (int i = d; i < TSTEPS - 1; i += DDIM) {
        float t0 = t[i];
        float t1 = t[i + 1];
        float dt = t1 - t0;
        plds[i] = make_float2(dt, sqrtf(dt) * invG);
    }

    const int lo = d & 31;
    const int hh = d >> 5;            // my half (0: j=0..31, 1: j=32..63)

    // Folded weight pairs over MY j-half: W2s = -2*K2L*W.
    // Wa: column lo, Wb: column lo+32.
    f32x2 Wa[16], Wb[16];
#pragma unroll
    for (int c = 0; c < 16; ++c) {
        int j = 32 * hh + 2 * c;
        Wa[c].x = -2.0f * K2L * Weff[(1 + j) * DDIM + lo];
        Wa[c].y = -2.0f * K2L * Weff[(2 + j) * DDIM + lo];
        Wb[c].x = -2.0f * K2L * Weff[(1 + j) * DDIM + lo + 32];
        Wb[c].y = -2.0f * K2L * Weff[(2 + j) * DDIM + lo + 32];
    }
    const float wts   = K2L * Weff[d];             // scaled t-coefficient (col d)
    const float biass = K2L * Weff[65 * DDIM + d]; // scaled folded bias   (col d)
    float Cd = 0.0f;                               // K2L * colsum (col d)
    for (int j = 0; j < DDIM; ++j) Cd += Weff[(1 + j) * DDIM + d];
    Cd *= K2L;

    // Calibrate permlane32_swap for the half-combine (r14-proven).
    auto cal = __builtin_amdgcn_permlane32_swap(d, d, false, false);
    const bool pick0 = (cal[0] == (d ^ 32));

    const unsigned yAbase = (unsigned)(uintptr_t)&yAl[0];
    const unsigned yBbase = (unsigned)(uintptr_t)&yBl[0];
    const unsigned waddrA = yAbase + 4u * (unsigned)d;
    const unsigned waddrB = yBbase + 4u * (unsigned)d;
    const unsigned rbaseA = yAbase + 128u * (unsigned)hh;
    const unsigned rbaseB = yBbase + 128u * (unsigned)hh;
    const unsigned pbase  = (unsigned)(uintptr_t)&plds[0];
    const float t0g = t[0];

    float yA = x[bA * DDIM + d];
    float yB = x[(bA + 1) * DDIM + d];
    float* opA = out + (size_t)bA * TSTEPS * DDIM + d;
    float* opB = opA + (size_t)TSTEPS * DDIM;
    *opA = yA;                                    // solution[:,0,:] = x
    *opB = yB;

#define READS8(r0,r1,r2,r3,r4,r5,r6,r7, BASE)                             \
    asm volatile(                                                         \
        "ds_read_b128 %[o0], %[a] offset:0\n\t"                           \
        "ds_read_b128 %[o1], %[a] offset:16\n\t"                          \
        "ds_read_b128 %[o2], %[a] offset:32\n\t"                          \
        "ds_read_b128 %[o3], %[a] offset:48\n\t"                          \
        "ds_read_b128 %[o4], %[a] offset:64\n\t"                          \
        "ds_read_b128 %[o5], %[a] offset:80\n\t"                          \
        "ds_read_b128 %[o6], %[a] offset:96\n\t"                          \
        "ds_read_b128 %[o7], %[a] offset:112"                             \
        : [o0] "=&v"(r0), [o1] "=&v"(r1), [o2] "=&v"(r2), [o3] "=&v"(r3), \
          [o4] "=&v"(r4), [o5] "=&v"(r5), [o6] "=&v"(r6), [o7] "=&v"(r7)  \
        : [a] "v"(BASE))

    // 8 quads -> dot for column d (32 pkfma + reduce + one permlane32_swap)
#define DOT_TAIL(v0,v1,v2,v3,v4,v5,v6,v7, DOTOUT)                         \
    {                                                                     \
        f32x2 accA0 = {0.f, 0.f}, accA1 = {0.f, 0.f};                     \
        f32x2 accB0 = {0.f, 0.f}, accB1 = {0.f, 0.f};                     \
        f32x4 vv_[8] = {v0, v1, v2, v3, v4, v5, v6, v7};                  \
        _Pragma("unroll")                                                 \
        for (int c = 0; c < 8; ++c) {                                     \
            f32x2 qlo = __builtin_shufflevector(vv_[c], vv_[c], 0, 1);    \
            f32x2 qhi = __builtin_shufflevector(vv_[c], vv_[c], 2, 3);    \
            pkfma(accA0, qlo, Wa[2 * c + 0]);                             \
            pkfma(accA1, qhi, Wa[2 * c + 1]);                             \
            pkfma(accB0, qlo, Wb[2 * c + 0]);                             \
            pkfma(accB1, qhi, Wb[2 * c + 1]);                             \
        }                                                                 \
        f32x2 ra = accA0 + accA1;                                         \
        f32x2 rb = accB0 + accB1;                                         \
        float qa = ra.x + ra.y;                                           \
        float qb = rb.x + rb.y;                                           \
        float keep = (d < 32) ? qa : qb;                                  \
        float send = (d < 32) ? qb : qa;                                  \
        auto sw2 = __builtin_amdgcn_permlane32_swap(__float_as_int(send), \
                                         __float_as_int(send), false, false);\
        float recv = __int_as_float(pick0 ? sw2[0] : sw2[1]);             \
        DOTOUT = keep + recv;                                             \
    }

    // ---- peel: s0 = biass + t0*wts + K2L*(W@y0) = base0 - 0.5*(W2s@y0) ----
    float sA, sB, rA, rB;
    {
        asm volatile("s_waitcnt lgkmcnt(0)" ::: "memory");  // staging done
        asm volatile("ds_write_b32 %0, %1" :: "v"(waddrA), "v"(yA));
        asm volatile("ds_write_b32 %0, %1" :: "v"(waddrB), "v"(yB));
        f32x4 a0, a1, a2, a3, a4, a5, a6, a7;
        f32x4 b0, b1, b2, b3, b4, b5, b6, b7;
        READS8(a0, a1, a2, a3, a4, a5, a6, a7, rbaseA);
        READS8(b0, b1, b2, b3, b4, b5, b6, b7, rbaseB);
        float base0 = fmaf(t0g, wts, biass);
        asm volatile("s_waitcnt lgkmcnt(0)" ::: "memory");
        __builtin_amdgcn_sched_barrier(0);
        float dotYA, dotYB;
        DOT_TAIL(a0, a1, a2, a3, a4, a5, a6, a7, dotYA);
        DOT_TAIL(b0, b1, b2, b3, b4, b5, b6, b7, dotYB);
        sA = fmaf(-0.5f, dotYA, base0);
        sB = fmaf(-0.5f, dotYB, base0);
        rA = __builtin_amdgcn_rcpf(__builtin_amdgcn_exp2f(sA) + 1.0f);
        rB = __builtin_amdgcn_rcpf(__builtin_amdgcn_exp2f(sB) + 1.0f);
    }

    f32x2 prm;                                    // (dt_k, f_k)
    prm.x = plds[0].x;
    prm.y = plds[0].y;

    for (int k = 0; k < TSTEPS - 1; ++k) {
        // ---- issue all DS ops (order = count): wA, rA*8, wB, rB*8, p = 19
        asm volatile("ds_write_b32 %0, %1" :: "v"(waddrA), "v"(rA));
        f32x4 a0, a1, a2, a3, a4, a5, a6, a7;
        READS8(a0, a1, a2, a3, a4, a5, a6, a7, rbaseA);
        asm volatile("ds_write_b32 %0, %1" :: "v"(waddrB), "v"(rB));
        f32x4 b0, b1, b2, b3, b4, b5, b6, b7;
        READS8(b0, b1, b2, b3, b4, b5, b6, b7, rbaseB);
        f32x2 prmn;
        unsigned paddr = pbase + 8u * (unsigned)(k + 1);
        asm volatile("ds_read_b64 %0, %1" : "=&v"(prmn) : "v"(paddr));

        // ---- off-chain: s-constants, y updates, stores (fills read latency)
        float dt = prm.x, f = prm.y;
        float scA = fmaf(f, Cd, fmaf(dt, wts, sA));
        float scB = fmaf(f, Cd, fmaf(dt, wts, sB));
        float m2f = -2.0f * f;
        yA = fmaf(m2f, rA, yA + f);               // y_{k+1} = y + f*(1-2r)
        yB = fmaf(m2f, rB, yB + f);
        opA += DDIM; *opA = yA;                   // fire-and-forget stores
        opB += DDIM; *opB = yB;

        // ---- row A: wait its 9 oldest (wA + rA*8) ----
        asm volatile("s_waitcnt lgkmcnt(10)" ::: "memory");
        __builtin_amdgcn_sched_barrier(0);
        float dotA;
        DOT_TAIL(a0, a1, a2, a3, a4, a5, a6, a7, dotA);
        sA = fmaf(f, dotA, scA);                  // s_A^{k+1}
        rA = __builtin_amdgcn_rcpf(__builtin_amdgcn_exp2f(sA) + 1.0f);

        // ---- row B: reads covered by A's compute ----
        asm volatile("s_waitcnt lgkmcnt(1)" ::: "memory");
        __builtin_amdgcn_sched_barrier(0);
        float dotB;
        DOT_TAIL(b0, b1, b2, b3, b4, b5, b6, b7, dotB);
        sB = fmaf(f, dotB, scB);                  // s_B^{k+1}
        rB = __builtin_amdgcn_rcpf(__builtin_amdgcn_exp2f(sB) + 1.0f);

        asm volatile("s_waitcnt lgkmcnt(0)" ::: "memory");  // prmn arrived
        __builtin_amdgcn_sched_barrier(0);
        prm = prmn;
    }
#undef DOT_TAIL
#undef READS8
}

extern "C" void kernel_launch(void* const* d_in, const int* in_sizes, int n_in,
                              void* d_out, int out_size, void* d_ws, size_t ws_size,
                              hipStream_t stream) {
    const float* x  = (const float*)d_in[0];
    const float* t  = (const float*)d_in[1];
    const float* W0 = (const float*)d_in[2];
    const float* b0 = (const float*)d_in[3];
    const float* W1 = (const float*)d_in[4];
    const float* b1 = (const float*)d_in[5];
    const float* W2 = (const float*)d_in[6];
    const float* b2 = (const float*)d_in[7];
    const float* W3 = (const float*)d_in[8];
    const float* b3 = (const float*)d_in[9];
    float* out = (float*)d_out;

    float* buf1 = (float*)d_ws;            // 66*256 floats
    float* buf2 = buf1 + AROWS * HDIM;     // 66*256 floats
    float* buf3 = buf2 + AROWS * HDIM;     // 66*64 floats

    compose1<<<AROWS, HDIM, 0, stream>>>(W0, b0, W1, b1, buf1);
    compose2<<<AROWS, HDIM, 0, stream>>>(buf1, W2, b2, buf2);
    compose3<<<AROWS, DDIM, 0, stream>>>(buf2, W3, b3, buf3);
    fode_scan<<<BROWS / 2, DDIM, 0, stream>>>(x, t, buf3, out);
}

// Round 17
// 229.504 us; speedup vs baseline: 1.5475x; 1.5475x over previous
//
#include <hip/hip_runtime.h>
#include <math.h>

// Sizes fixed by the reference: B=512, T=1024, D_IN=D_OUT=64, H=256.
#define HDIM 256
#define DDIM 64
#define BROWS 512
#define TSTEPS 1024
// Augmented rows: 65 weight rows (t-row + 64 state rows) + 1 bias row.
#define AROWS 66

typedef float f32x2 __attribute__((ext_vector_type(2)));
typedef float f32x4 __attribute__((ext_vector_type(4)));

// ---- Setup: compose the linear MLP into one 66x64 affine map ----
__global__ void compose1(const float* __restrict__ W0, const float* __restrict__ b0,
                         const float* __restrict__ W1, const float* __restrict__ b1,
                         float* __restrict__ out1) {
    int r = blockIdx.x;    // 0..65
    int c = threadIdx.x;   // 0..255
    const float* arow = (r < 65) ? (W0 + r * HDIM) : b0;
    float acc = (r == 65) ? b1[c] : 0.0f;
    for (int h = 0; h < HDIM; ++h)
        acc = fmaf(arow[h], W1[h * HDIM + c], acc);
    out1[r * HDIM + c] = acc;
}

__global__ void compose2(const float* __restrict__ in1,
                         const float* __restrict__ W2, const float* __restrict__ b2,
                         float* __restrict__ out2) {
    int r = blockIdx.x, c = threadIdx.x;
    const float* arow = in1 + r * HDIM;
    float acc = (r == 65) ? b2[c] : 0.0f;
    for (int h = 0; h < HDIM; ++h)
        acc = fmaf(arow[h], W2[h * HDIM + c], acc);
    out2[r * HDIM + c] = acc;
}

__global__ void compose3(const float* __restrict__ in2,
                         const float* __restrict__ W3, const float* __restrict__ b3,
                         float* __restrict__ out3) {
    int r = blockIdx.x, c = threadIdx.x;   // c 0..63
    const float* arow = in2 + r * HDIM;
    float acc = (r == 65) ? b3[c] : 0.0f;
    for (int h = 0; h < HDIM; ++h)
        acc = fmaf(arow[h], W3[h * DDIM + c], acc);
    out3[r * DDIM + c] = acc;
}

// Packed 2xf32 FMA: acc.lo += a.lo*b.lo; acc.hi += a.hi*b.hi  (VOP3P, CDNA)
__device__ __forceinline__ void pkfma(f32x2& acc, f32x2 a, f32x2 b) {
    asm("v_pk_fma_f32 %0, %1, %2, %0" : "+v"(acc) : "v"(a), "v"(b));
}

// ---- Main scan: one wave per batch row, lane = output dim ----
//
// r16 lesson: wall = ONE row's serial per-step chain (512 waves co-resident;
// multi-row waves lengthen the iteration). This round keeps r14's proven
// structure (524 cyc/step) and trims issue overhead on the chain:
//  - 2-step unroll, params packed (dt0,f0,dt1,f1) in one b128 prefetch per
//    pair (halves param reads/waits, amortizes loop branch)
//  - combine reorder: swap 'send' early; fma(f,keep,sc) runs under the
//    permlane32_swap latency
//  - final step (k=1022) elided to y-update+store only (its dot is unused)
// Numerics = r16's proven folding: broadcast r=rcp(exp2(s)+1), W2s=-2*K2L*W,
// colsum Cd; s-recurrence s' = s + dt*wts + f*Cd + f*(W2s@r).
__launch_bounds__(64, 1)
__global__ void fode_scan(const float* __restrict__ x, const float* __restrict__ t,
                          const float* __restrict__ Weff,   // 66 x 64 composed
                          float* __restrict__ out) {
    const int b = blockIdx.x;
    const int d = threadIdx.x;   // 0..63

    __shared__ __align__(16) float ylds[DDIM];
    __shared__ __align__(16) float4 plds4[TSTEPS / 2];  // (dt0,f0,dt1,f1) per pair

    const float invG = 0.56418958354775628695f;   // 1/Gamma(0.5)
    const float K2L = 2.88539008177792681472f;    // 2*log2(e)

    // Stage per-pair params: 8 coalesced iterations.
    for (int i = d; i < TSTEPS / 2; i += DDIM) {
        int k0 = 2 * i, k1 = 2 * i + 1;
        float ta = t[k0], tb = t[k0 + 1];
        float dt0 = tb - ta;
        float f0 = sqrtf(dt0) * invG;
        float dt1 = 0.f, f1 = 0.f;
        if (k1 + 1 < TSTEPS) {
            float tc = t[k1 + 1];
            dt1 = tc - tb;
            f1 = sqrtf(dt1) * invG;
        }
        plds4[i] = make_float4(dt0, f0, dt1, f1);
    }

    const int lo = d & 31;
    const int hh = d >> 5;            // my half (0: j=0..31, 1: j=32..63)

    // Folded weight pairs over MY j-half: W2s = -2*K2L*W.
    // Wa: column lo, Wb: column lo+32.
    f32x2 Wa[16], Wb[16];
#pragma unroll
    for (int c = 0; c < 16; ++c) {
        int j = 32 * hh + 2 * c;
        Wa[c].x = -2.0f * K2L * Weff[(1 + j) * DDIM + lo];
        Wa[c].y = -2.0f * K2L * Weff[(2 + j) * DDIM + lo];
        Wb[c].x = -2.0f * K2L * Weff[(1 + j) * DDIM + lo + 32];
        Wb[c].y = -2.0f * K2L * Weff[(2 + j) * DDIM + lo + 32];
    }
    const float wts   = K2L * Weff[d];             // scaled t-coefficient (col d)
    const float biass = K2L * Weff[65 * DDIM + d]; // scaled folded bias   (col d)
    float Cd = 0.0f;                               // K2L * colsum (col d)
    for (int j = 0; j < DDIM; ++j) Cd += Weff[(1 + j) * DDIM + d];
    Cd *= K2L;

    // Calibrate permlane32_swap (r14-proven).
    auto cal = __builtin_amdgcn_permlane32_swap(d, d, false, false);
    const bool pick0 = (cal[0] == (d ^ 32));

    const unsigned ybase = (unsigned)(uintptr_t)&ylds[0];
    const unsigned waddr = ybase + 4u * (unsigned)d;
    const unsigned rbase = ybase + 128u * (unsigned)hh;   // my th/r half
    const unsigned pbase = (unsigned)(uintptr_t)&plds4[0];
    const float t0g = t[0];

    float y = x[b * DDIM + d];
    float* op = out + (size_t)b * TSTEPS * DDIM + d;
    *op = y;                                      // solution[:,0,:] = x

#define READS8(r0,r1,r2,r3,r4,r5,r6,r7)                                   \
    asm volatile(                                                         \
        "ds_read_b128 %[o0], %[a] offset:0\n\t"                           \
        "ds_read_b128 %[o1], %[a] offset:16\n\t"                          \
        "ds_read_b128 %[o2], %[a] offset:32\n\t"                          \
        "ds_read_b128 %[o3], %[a] offset:48\n\t"                          \
        "ds_read_b128 %[o4], %[a] offset:64\n\t"                          \
        "ds_read_b128 %[o5], %[a] offset:80\n\t"                          \
        "ds_read_b128 %[o6], %[a] offset:96\n\t"                          \
        "ds_read_b128 %[o7], %[a] offset:112"                             \
        : [o0] "=&v"(r0), [o1] "=&v"(r1), [o2] "=&v"(r2), [o3] "=&v"(r3), \
          [o4] "=&v"(r4), [o5] "=&v"(r5), [o6] "=&v"(r6), [o7] "=&v"(r7)  \
        : [a] "v"(rbase))

#define QUADH(vq, c)                                                      \
    {                                                                     \
        f32x2 qlo = __builtin_shufflevector(vq, vq, 0, 1);                \
        f32x2 qhi = __builtin_shufflevector(vq, vq, 2, 3);                \
        pkfma(accA0, qlo, Wa[2 * (c) + 0]);                               \
        pkfma(accA1, qhi, Wa[2 * (c) + 1]);                               \
        pkfma(accB0, qlo, Wb[2 * (c) + 0]);                               \
        pkfma(accB1, qhi, Wb[2 * (c) + 1]);                               \
    }

    // ---- peel: s_0 = biass + t_0*wts - 0.5*(W2s @ y_0) ----
    float s, r;
    {
        asm volatile("s_waitcnt lgkmcnt(0)" ::: "memory");  // staging done
        asm volatile("ds_write_b32 %0, %1" :: "v"(waddr), "v"(y));
        f32x4 v0, v1, v2, v3, v4, v5, v6, v7;
        READS8(v0, v1, v2, v3, v4, v5, v6, v7);
        float base0 = fmaf(t0g, wts, biass);
        asm volatile("s_waitcnt lgkmcnt(0)" ::: "memory");
        __builtin_amdgcn_sched_barrier(0);
        f32x2 accA0 = {0.f, 0.f}, accA1 = {0.f, 0.f};
        f32x2 accB0 = {0.f, 0.f}, accB1 = {0.f, 0.f};
        QUADH(v0, 0) QUADH(v1, 1) QUADH(v2, 2) QUADH(v3, 3)
        QUADH(v4, 4) QUADH(v5, 5) QUADH(v6, 6) QUADH(v7, 7)
        f32x2 ra = accA0 + accA1, rb = accB0 + accB1;
        float qa = ra.x + ra.y, qb = rb.x + rb.y;
        float send = (d < 32) ? qb : qa;
        auto sw2 = __builtin_amdgcn_permlane32_swap(__float_as_int(send),
                                                    __float_as_int(send), false, false);
        float keep = (d < 32) ? qa : qb;
        float base2 = fmaf(-0.5f, keep, base0);
        float recv = __int_as_float(pick0 ? sw2[0] : sw2[1]);
        s = fmaf(-0.5f, recv, base2);
        r = __builtin_amdgcn_rcpf(__builtin_amdgcn_exp2f(s) + 1.0f);
    }

    f32x4 prm4 = *(const f32x4*)&plds4[0];        // (dt0,f0,dt1,f1)

    // One step: write r, 8 reads [+optional param prefetch], off-chain
    // updates, counted waits, 32 pkfma, reordered combine, tanh.
#define STEP_BODY(DT, F, PREFETCH_STMT, W1CNT, W2CNT)                     \
    {                                                                     \
        asm volatile("ds_write_b32 %0, %1" :: "v"(waddr), "v"(r));        \
        f32x4 v0, v1, v2, v3, v4, v5, v6, v7;                             \
        READS8(v0, v1, v2, v3, v4, v5, v6, v7);                           \
        PREFETCH_STMT;                                                    \
        float dt = (DT), f = (F);                                         \
        float sc = fmaf(f, Cd, fmaf(dt, wts, s));                         \
        y = fmaf(-2.0f * f, r, y + f);                                    \
        op += DDIM;                                                       \
        *op = y;                                                          \
        f32x2 accA0 = {0.f, 0.f}, accA1 = {0.f, 0.f};                     \
        f32x2 accB0 = {0.f, 0.f}, accB1 = {0.f, 0.f};                     \
        asm volatile("s_waitcnt lgkmcnt(" #W1CNT ")" ::: "memory");       \
        __builtin_amdgcn_sched_barrier(0);                                \
        QUADH(v0, 0) QUADH(v1, 1) QUADH(v2, 2) QUADH(v3, 3)               \
        asm volatile("s_waitcnt lgkmcnt(" #W2CNT ")" ::: "memory");       \
        __builtin_amdgcn_sched_barrier(0);                                \
        QUADH(v4, 4) QUADH(v5, 5) QUADH(v6, 6) QUADH(v7, 7)               \
        f32x2 ra = accA0 + accA1, rb = accB0 + accB1;                     \
        float qa = ra.x + ra.y, qb = rb.x + rb.y;                         \
        float send = (d < 32) ? qb : qa;                                  \
        auto sw2 = __builtin_amdgcn_permlane32_swap(__float_as_int(send), \
                                         __float_as_int(send), false, false);\
        float keep = (d < 32) ? qa : qb;                                  \
        float base2 = fmaf(f, keep, sc);                                  \
        float recv = __int_as_float(pick0 ? sw2[0] : sw2[1]);             \
        s = fmaf(f, recv, base2);                                         \
        r = __builtin_amdgcn_rcpf(__builtin_amdgcn_exp2f(s) + 1.0f);      \
    }

    f32x4 prm4n;
    for (int i = 0; i < TSTEPS / 2 - 1; ++i) {    // 511 pairs: steps 0..1021
        // even step: outstanding after issue = w + 8r = 9
        STEP_BODY(prm4.x, prm4.y, , 4, 0)
        // odd step: + param prefetch => w + 8r + p = 10
        unsigned paddr = pbase + 16u * (unsigned)(i + 1);
        STEP_BODY(prm4.z, prm4.w,
                  asm volatile("ds_read_b128 %0, %1" : "=&v"(prm4n) : "v"(paddr)),
                  5, 1)
        asm volatile("s_waitcnt lgkmcnt(0)" ::: "memory");  // prm4n arrived
        __builtin_amdgcn_sched_barrier(0);
        prm4 = prm4n;
    }

    // final step k=1022: only y-update + store (its dot/s' would be unused)
    {
        float f = prm4.y;
        y = fmaf(-2.0f * f, r, y + f);
        op += DDIM;
        *op = y;
    }
#undef STEP_BODY
#undef QUADH
#undef READS8
}

extern "C" void kernel_launch(void* const* d_in, const int* in_sizes, int n_in,
                              void* d_out, int out_size, void* d_ws, size_t ws_size,
                              hipStream_t stream) {
    const float* x  = (const float*)d_in[0];
    const float* t  = (const float*)d_in[1];
    const float* W0 = (const float*)d_in[2];
    const float* b0 = (const float*)d_in[3];
    const float* W1 = (const float*)d_in[4];
    const float* b1 = (const float*)d_in[5];
    const float* W2 = (const float*)d_in[6];
    const float* b2 = (const float*)d_in[7];
    const float* W3 = (const float*)d_in[8];
    const float* b3 = (const float*)d_in[9];
    float* out = (float*)d_out;

    float* buf1 = (float*)d_ws;            // 66*256 floats
    float* buf2 = buf1 + AROWS * HDIM;     // 66*256 floats
    float* buf3 = buf2 + AROWS * HDIM;     // 66*64 floats

    compose1<<<AROWS, HDIM, 0, stream>>>(W0, b0, W1, b1, buf1);
    compose2<<<AROWS, HDIM, 0, stream>>>(buf1, W2, b2, buf2);
    compose3<<<AROWS, DDIM, 0, stream>>>(buf2, W3, b3, buf3);
    fode_scan<<<BROWS, DDIM, 0, stream>>>(x, t, buf3, out);
}